// Round 1
// baseline (2239.769 us; speedup 1.0000x reference)
//
#include <hip/hip_runtime.h>
#include <cstdint>
#include <cstddef>

#define N_NODES 50000
#define N_EDGES 800000
#define CH 512

// ---------------- CSR build ----------------

__global__ __launch_bounds__(256) void count_col(const int* __restrict__ col, int* __restrict__ cnt) {
    int e = blockIdx.x * 256 + threadIdx.x;
    if (e < N_EDGES) atomicAdd(&cnt[col[e]], 1);
}

__global__ __launch_bounds__(256) void make_dinv(const int* __restrict__ cnt, float* __restrict__ dinv) {
    int i = blockIdx.x * 256 + threadIdx.x;
    if (i < N_NODES) dinv[i] = rsqrtf((float)(cnt[i] + 1));  // +1 self loop
}

// Single-block exclusive scan over 50000 counts -> offs[0..50000]
__global__ __launch_bounds__(1024) void scan_offsets(const int* __restrict__ cnt, int* __restrict__ offs) {
    __shared__ int wsum[16];
    __shared__ int s_carry;
    int tid = threadIdx.x;
    int lane = tid & 63, wid = tid >> 6;
    if (tid == 0) s_carry = 0;
    __syncthreads();
    const int n = N_NODES;
    for (int c0 = 0; c0 < n; c0 += 1024) {
        int i = c0 + tid;
        int v = (i < n) ? cnt[i] : 0;
        int incl = v;
        #pragma unroll
        for (int d = 1; d < 64; d <<= 1) {
            int t = __shfl_up(incl, d, 64);
            if (lane >= d) incl += t;
        }
        if (lane == 63) wsum[wid] = incl;
        __syncthreads();
        int wbase = 0;
        for (int w = 0; w < wid; ++w) wbase += wsum[w];
        int excl = s_carry + wbase + incl - v;
        if (i < n) offs[i] = excl;
        int ctot = wbase + incl;  // meaningful for tid==1023
        __syncthreads();
        if (tid == 1023) s_carry += ctot;
        __syncthreads();
    }
    if (tid == 0) offs[n] = s_carry;
}

__global__ __launch_bounds__(256) void fill_csr(const int* __restrict__ edges,
                                                const int* __restrict__ offs,
                                                int* __restrict__ cursor,
                                                const float* __restrict__ dinv,
                                                int* __restrict__ srcs,
                                                float* __restrict__ enorm) {
    int e = blockIdx.x * 256 + threadIdx.x;
    if (e >= N_EDGES) return;
    int r = edges[e];            // source
    int c = edges[N_EDGES + e];  // destination
    int p = offs[c] + atomicAdd(&cursor[c], 1);
    srcs[p] = r;
    enorm[p] = dinv[r] * dinv[c];
}

// ---------------- Propagation: out[i] = dinv[i]^2 * h[i] + sum_e enorm[e]*h[src[e]] ----------------

__global__ __launch_bounds__(128) void propagate(const float* __restrict__ h, float* __restrict__ out,
                                                 const int* __restrict__ offs,
                                                 const int* __restrict__ srcs,
                                                 const float* __restrict__ enorm,
                                                 const float* __restrict__ dinv) {
    int node = blockIdx.x;
    int t = threadIdx.x;  // 128 threads * float4 = 512 channels
    const float4* h4 = (const float4*)h;
    float di = dinv[node];
    float w0 = di * di;
    float4 v = h4[(size_t)node * 128 + t];
    float4 acc = make_float4(v.x * w0, v.y * w0, v.z * w0, v.w * w0);
    int e0 = offs[node], e1 = offs[node + 1];
    for (int e = e0; e < e1; ++e) {
        int s = srcs[e];
        float w = enorm[e];
        float4 u = h4[(size_t)s * 128 + t];
        acc.x += u.x * w;
        acc.y += u.y * w;
        acc.z += u.z * w;
        acc.w += u.w * w;
    }
    ((float4*)out)[(size_t)node * 128 + t] = acc;
}

// ---------------- fp32 GEMM: C[M,512] = A[M,512] @ W[512,512] + bias ----------------

#define BM 64
#define BN 64
#define BK 16

__global__ __launch_bounds__(256) void gemm_bias(const float* __restrict__ A, const float* __restrict__ W,
                                                 const float* __restrict__ bias, float* __restrict__ C) {
    __shared__ float Ast[BK][BM + 4];  // A tile transposed: Ast[k][m]
    __shared__ float Ws[BK][BN + 4];
    int tid = threadIdx.x;
    int bm = blockIdx.x * BM;
    int bn = blockIdx.y * BN;
    int tx = tid & 15, ty = tid >> 4;
    float acc[4][4] = {};

    int ar = tid >> 2;        // 0..63 row within tile
    int ak = (tid & 3) * 4;   // 0,4,8,12 k within tile
    int wr = tid >> 4;        // 0..15 k within tile
    int wc = (tid & 15) * 4;  // 0..60 col within tile
    int arow = bm + ar;
    bool aval = arow < N_NODES;

    for (int k0 = 0; k0 < CH; k0 += BK) {
        float4 av = make_float4(0.f, 0.f, 0.f, 0.f);
        if (aval) av = *(const float4*)&A[(size_t)arow * CH + k0 + ak];
        float4 wv = *(const float4*)&W[(size_t)(k0 + wr) * CH + bn + wc];
        Ast[ak + 0][ar] = av.x;
        Ast[ak + 1][ar] = av.y;
        Ast[ak + 2][ar] = av.z;
        Ast[ak + 3][ar] = av.w;
        *(float4*)&Ws[wr][wc] = wv;
        __syncthreads();
        #pragma unroll
        for (int k = 0; k < BK; ++k) {
            float4 a = *(const float4*)&Ast[k][ty * 4];
            float4 w = *(const float4*)&Ws[k][tx * 4];
            float as[4] = {a.x, a.y, a.z, a.w};
            float wsv[4] = {w.x, w.y, w.z, w.w};
            #pragma unroll
            for (int i = 0; i < 4; ++i)
                #pragma unroll
                for (int j = 0; j < 4; ++j)
                    acc[i][j] += as[i] * wsv[j];
        }
        __syncthreads();
    }

    float4 bv = *(const float4*)&bias[bn + tx * 4];
    #pragma unroll
    for (int i = 0; i < 4; ++i) {
        int row = bm + ty * 4 + i;
        if (row < N_NODES) {
            float4 o = make_float4(acc[i][0] + bv.x, acc[i][1] + bv.y,
                                   acc[i][2] + bv.z, acc[i][3] + bv.w);
            *(float4*)&C[(size_t)row * CH + bn + tx * 4] = o;
        }
    }
}

// ---------------- Softmax (+argmax for conv1), one wave per row ----------------

__global__ __launch_bounds__(256) void softmax_rows(const float* __restrict__ X, float* __restrict__ P,
                                                    float* __restrict__ preds) {
    int row = blockIdx.x * 4 + (threadIdx.x >> 6);
    int lane = threadIdx.x & 63;
    if (row >= N_NODES) return;
    const float4* x4 = (const float4*)(X + (size_t)row * CH);
    float4 v0 = x4[lane];
    float4 v1 = x4[lane + 64];
    float vals[8] = {v0.x, v0.y, v0.z, v0.w, v1.x, v1.y, v1.z, v1.w};
    float m = vals[0];
    int mi = lane * 4;
    #pragma unroll
    for (int j = 1; j < 8; ++j) {
        int c = (j < 4) ? (lane * 4 + j) : (256 + lane * 4 + (j - 4));
        if (vals[j] > m) { m = vals[j]; mi = c; }
    }
    #pragma unroll
    for (int d = 32; d > 0; d >>= 1) {
        float om = __shfl_xor(m, d, 64);
        int oi = __shfl_xor(mi, d, 64);
        if (om > m || (om == m && oi < mi)) { m = om; mi = oi; }
    }
    float s = 0.f;
    float ex[8];
    #pragma unroll
    for (int j = 0; j < 8; ++j) { ex[j] = __expf(vals[j] - m); s += ex[j]; }
    #pragma unroll
    for (int d = 32; d > 0; d >>= 1) s += __shfl_xor(s, d, 64);
    float inv = 1.0f / s;
    float4 o0 = make_float4(ex[0] * inv, ex[1] * inv, ex[2] * inv, ex[3] * inv);
    float4 o1 = make_float4(ex[4] * inv, ex[5] * inv, ex[6] * inv, ex[7] * inv);
    float4* p4 = (float4*)(P + (size_t)row * CH);
    p4[lane] = o0;
    p4[lane + 64] = o1;
    if (preds != nullptr && lane == 0) preds[row] = (float)mi;
}

// ---------------- launcher ----------------

extern "C" void kernel_launch(void* const* d_in, const int* in_sizes, int n_in,
                              void* d_out, int out_size, void* d_ws, size_t ws_size,
                              hipStream_t stream) {
    const float* x  = (const float*)d_in[0];
    const int*   e1 = (const int*)d_in[1];
    const int*   e2 = (const int*)d_in[2];
    const float* W1 = (const float*)d_in[3];
    const float* b1 = (const float*)d_in[4];
    const float* W2 = (const float*)d_in[5];
    const float* b2 = (const float*)d_in[6];

    float* out     = (float*)d_out;
    float* logits1 = out;
    float* logits2 = out + (size_t)N_NODES * CH;
    float* preds   = out + 2 * (size_t)N_NODES * CH;

    // Workspace layout (bytes):
    //   A      @ 0            : 102,400,000   (50000*512 f32 scratch)
    //   cnt    @ 102,400,000  :     200,000
    //   offs   @ 102,600,000  :     200,004
    //   cursor @ 102,800,016  :     200,000
    //   dinv   @ 103,000,016  :     200,000
    //   srcs   @ 103,200,016  :   3,200,000
    //   enorm  @ 106,400,016  :   3,200,000   -> total 109,600,016
    const size_t NEED = 109600016;
    if (ws_size < NEED) return;  // fail loudly (poisoned output) rather than corrupt

    char* ws = (char*)d_ws;
    float* A      = (float*)(ws);
    int*   cnt    = (int*)(ws + 102400000);
    int*   offs   = (int*)(ws + 102600000);
    int*   cursor = (int*)(ws + 102800016);
    float* dinv   = (float*)(ws + 103000016);
    int*   srcs   = (int*)(ws + 103200016);
    float* enorm  = (float*)(ws + 106400016);

    for (int conv = 0; conv < 2; ++conv) {
        const int*   edges = conv ? e2 : e1;
        const float* Wm    = conv ? W2 : W1;
        const float* bvec  = conv ? b2 : b1;
        float*       O     = conv ? logits2 : logits1;

        hipMemsetAsync(cnt, 0, N_NODES * sizeof(int), stream);
        hipMemsetAsync(cursor, 0, N_NODES * sizeof(int), stream);
        count_col<<<(N_EDGES + 255) / 256, 256, 0, stream>>>(edges + N_EDGES, cnt);
        make_dinv<<<(N_NODES + 255) / 256, 256, 0, stream>>>(cnt, dinv);
        scan_offsets<<<1, 1024, 0, stream>>>(cnt, offs);
        fill_csr<<<(N_EDGES + 255) / 256, 256, 0, stream>>>(edges, offs, cursor, dinv, srcs, enorm);

        // h1 = A_hat x   (uses output region as scratch)
        propagate<<<N_NODES, 128, 0, stream>>>(x, O, offs, srcs, enorm, dinv);
        // h2 = A_hat h1
        propagate<<<N_NODES, 128, 0, stream>>>(O, A, offs, srcs, enorm, dinv);
        // O = h2 @ W + b
        dim3 g((N_NODES + BM - 1) / BM, CH / BN);
        gemm_bias<<<g, 256, 0, stream>>>(A, Wm, bvec, O);
        // softmax rows in-place (+argmax predictions for conv 0)
        softmax_rows<<<N_NODES / 4, 256, 0, stream>>>(O, O, conv == 0 ? preds : nullptr);
    }
}

// Round 2
// 1792.770 us; speedup vs baseline: 1.2493x; 1.2493x over previous
//
#include <hip/hip_runtime.h>
#include <hip/hip_bf16.h>
#include <cstdint>
#include <cstddef>

#define N_NODES 50000
#define N_EDGES 800000
#define CH 512

typedef __attribute__((ext_vector_type(8))) short bf16x8;
typedef __attribute__((ext_vector_type(4))) float f32x4;

__device__ inline unsigned short f2b(float f) {
    __hip_bfloat16 h = __float2bfloat16(f);
    return *(unsigned short*)&h;
}
__device__ inline float blo(unsigned int u) {  // low 16 bits as bf16 -> f32
    union { unsigned int i; float f; } v; v.i = u << 16; return v.f;
}
__device__ inline float bhi(unsigned int u) {  // high 16 bits as bf16 -> f32
    union { unsigned int i; float f; } v; v.i = u & 0xffff0000u; return v.f;
}

// ---------------- CSR build ----------------

__global__ __launch_bounds__(256) void count_col(const int* __restrict__ col, int* __restrict__ cnt) {
    int e = blockIdx.x * 256 + threadIdx.x;
    if (e < N_EDGES) atomicAdd(&cnt[col[e]], 1);
}

__global__ __launch_bounds__(256) void make_dinv(const int* __restrict__ cnt, float* __restrict__ dinv) {
    int i = blockIdx.x * 256 + threadIdx.x;
    if (i < N_NODES) dinv[i] = rsqrtf((float)(cnt[i] + 1));  // +1 self loop
}

__global__ __launch_bounds__(1024) void scan_offsets(const int* __restrict__ cnt, int* __restrict__ offs) {
    __shared__ int wsum[16];
    __shared__ int s_carry;
    int tid = threadIdx.x;
    int lane = tid & 63, wid = tid >> 6;
    if (tid == 0) s_carry = 0;
    __syncthreads();
    const int n = N_NODES;
    for (int c0 = 0; c0 < n; c0 += 1024) {
        int i = c0 + tid;
        int v = (i < n) ? cnt[i] : 0;
        int incl = v;
        #pragma unroll
        for (int d = 1; d < 64; d <<= 1) {
            int t = __shfl_up(incl, d, 64);
            if (lane >= d) incl += t;
        }
        if (lane == 63) wsum[wid] = incl;
        __syncthreads();
        int wbase = 0;
        for (int w = 0; w < wid; ++w) wbase += wsum[w];
        int excl = s_carry + wbase + incl - v;
        if (i < n) offs[i] = excl;
        int ctot = wbase + incl;
        __syncthreads();
        if (tid == 1023) s_carry += ctot;
        __syncthreads();
    }
    if (tid == 0) offs[n] = s_carry;
}

__global__ __launch_bounds__(256) void fill_csr(const int* __restrict__ edges,
                                                const int* __restrict__ offs,
                                                int* __restrict__ cursor,
                                                const float* __restrict__ dinv,
                                                int* __restrict__ srcs,
                                                float* __restrict__ enorm) {
    int e = blockIdx.x * 256 + threadIdx.x;
    if (e >= N_EDGES) return;
    int r = edges[e];            // source
    int c = edges[N_EDGES + e];  // destination
    int p = offs[c] + atomicAdd(&cursor[c], 1);
    srcs[p] = r;
    enorm[p] = dinv[r] * dinv[c];
}

// ---------------- converters ----------------

__global__ __launch_bounds__(256) void convert_x_bf16(const float* __restrict__ x, unsigned short* __restrict__ xb) {
    int i8 = blockIdx.x * 256 + threadIdx.x;  // 8 floats per thread; grid covers 25.6M/8
    const float4* x4 = (const float4*)x;
    float4 a = x4[2 * i8], b = x4[2 * i8 + 1];
    unsigned int o[4];
    o[0] = (unsigned)f2b(a.x) | ((unsigned)f2b(a.y) << 16);
    o[1] = (unsigned)f2b(a.z) | ((unsigned)f2b(a.w) << 16);
    o[2] = (unsigned)f2b(b.x) | ((unsigned)f2b(b.y) << 16);
    o[3] = (unsigned)f2b(b.z) | ((unsigned)f2b(b.w) << 16);
    ((uint4*)xb)[i8] = make_uint4(o[0], o[1], o[2], o[3]);
}

// Wt[n][k] = bf16(W[k][n])  (n-major so MFMA B-fragments are contiguous in k)
__global__ __launch_bounds__(256) void convert_w_t(const float* __restrict__ W, unsigned short* __restrict__ Wt) {
    int id = blockIdx.x * 256 + threadIdx.x;  // 262144 threads
    int k = id >> 9, n = id & 511;
    Wt[(size_t)n * 512 + k] = f2b(W[(size_t)k * 512 + n]);
}

// ---------------- fp32 propagation (conv1): unroll-4 gather ----------------

__global__ __launch_bounds__(128) void propagate(const float* __restrict__ h, float* __restrict__ out,
                                                 const int* __restrict__ offs,
                                                 const int* __restrict__ srcs,
                                                 const float* __restrict__ enorm,
                                                 const float* __restrict__ dinv) {
    int node = blockIdx.x;
    int t = threadIdx.x;  // 128 threads * float4 = 512 channels
    const float4* h4 = (const float4*)h;
    float di = dinv[node];
    float w0 = di * di;
    float4 v = h4[(size_t)node * 128 + t];
    float4 acc = make_float4(v.x * w0, v.y * w0, v.z * w0, v.w * w0);
    int e0 = offs[node], e1 = offs[node + 1];
    int e = e0;
    int eu = e0 + ((e1 - e0) & ~3);
    for (; e < eu; e += 4) {
        int s0 = srcs[e], s1 = srcs[e + 1], s2 = srcs[e + 2], s3 = srcs[e + 3];
        float wa = enorm[e], wb = enorm[e + 1], wc = enorm[e + 2], wd = enorm[e + 3];
        float4 u0 = h4[(size_t)s0 * 128 + t];
        float4 u1 = h4[(size_t)s1 * 128 + t];
        float4 u2 = h4[(size_t)s2 * 128 + t];
        float4 u3 = h4[(size_t)s3 * 128 + t];
        acc.x += u0.x * wa; acc.y += u0.y * wa; acc.z += u0.z * wa; acc.w += u0.w * wa;
        acc.x += u1.x * wb; acc.y += u1.y * wb; acc.z += u1.z * wb; acc.w += u1.w * wb;
        acc.x += u2.x * wc; acc.y += u2.y * wc; acc.z += u2.z * wc; acc.w += u2.w * wc;
        acc.x += u3.x * wd; acc.y += u3.y * wd; acc.z += u3.z * wd; acc.w += u3.w * wd;
    }
    for (; e < e1; ++e) {
        int s = srcs[e];
        float w = enorm[e];
        float4 u = h4[(size_t)s * 128 + t];
        acc.x += u.x * w; acc.y += u.y * w; acc.z += u.z * w; acc.w += u.w * w;
    }
    ((float4*)out)[(size_t)node * 128 + t] = acc;
}

// ---------------- bf16 propagation (conv2): wave per node, fp32 accum ----------------

__global__ __launch_bounds__(128) void propagate_bf16(const unsigned short* __restrict__ hb,
                                                      unsigned short* __restrict__ outb,
                                                      const int* __restrict__ offs,
                                                      const int* __restrict__ srcs,
                                                      const float* __restrict__ enorm,
                                                      const float* __restrict__ dinv) {
    int node = blockIdx.x * 2 + (threadIdx.x >> 6);
    int lane = threadIdx.x & 63;  // lane handles 8 channels (16 B)
    const uint4* h16 = (const uint4*)hb;  // 64 uint4 per row
    float di = dinv[node];
    float w0 = di * di;
    float acc[8];
    uint4 sv = h16[(size_t)node * 64 + lane];
    acc[0] = blo(sv.x) * w0; acc[1] = bhi(sv.x) * w0;
    acc[2] = blo(sv.y) * w0; acc[3] = bhi(sv.y) * w0;
    acc[4] = blo(sv.z) * w0; acc[5] = bhi(sv.z) * w0;
    acc[6] = blo(sv.w) * w0; acc[7] = bhi(sv.w) * w0;
    int e0 = offs[node], e1 = offs[node + 1];
    int e = e0;
    int eu = e0 + ((e1 - e0) & ~3);
    for (; e < eu; e += 4) {
        int s0 = srcs[e], s1 = srcs[e + 1], s2 = srcs[e + 2], s3 = srcs[e + 3];
        float wa = enorm[e], wb = enorm[e + 1], wc = enorm[e + 2], wd = enorm[e + 3];
        uint4 u0 = h16[(size_t)s0 * 64 + lane];
        uint4 u1 = h16[(size_t)s1 * 64 + lane];
        uint4 u2 = h16[(size_t)s2 * 64 + lane];
        uint4 u3 = h16[(size_t)s3 * 64 + lane];
        acc[0] += blo(u0.x) * wa; acc[1] += bhi(u0.x) * wa;
        acc[2] += blo(u0.y) * wa; acc[3] += bhi(u0.y) * wa;
        acc[4] += blo(u0.z) * wa; acc[5] += bhi(u0.z) * wa;
        acc[6] += blo(u0.w) * wa; acc[7] += bhi(u0.w) * wa;
        acc[0] += blo(u1.x) * wb; acc[1] += bhi(u1.x) * wb;
        acc[2] += blo(u1.y) * wb; acc[3] += bhi(u1.y) * wb;
        acc[4] += blo(u1.z) * wb; acc[5] += bhi(u1.z) * wb;
        acc[6] += blo(u1.w) * wb; acc[7] += bhi(u1.w) * wb;
        acc[0] += blo(u2.x) * wc; acc[1] += bhi(u2.x) * wc;
        acc[2] += blo(u2.y) * wc; acc[3] += bhi(u2.y) * wc;
        acc[4] += blo(u2.z) * wc; acc[5] += bhi(u2.z) * wc;
        acc[6] += blo(u2.w) * wc; acc[7] += bhi(u2.w) * wc;
        acc[0] += blo(u3.x) * wd; acc[1] += bhi(u3.x) * wd;
        acc[2] += blo(u3.y) * wd; acc[3] += bhi(u3.y) * wd;
        acc[4] += blo(u3.z) * wd; acc[5] += bhi(u3.z) * wd;
        acc[6] += blo(u3.w) * wd; acc[7] += bhi(u3.w) * wd;
    }
    for (; e < e1; ++e) {
        int s = srcs[e];
        float w = enorm[e];
        uint4 u = h16[(size_t)s * 64 + lane];
        acc[0] += blo(u.x) * w; acc[1] += bhi(u.x) * w;
        acc[2] += blo(u.y) * w; acc[3] += bhi(u.y) * w;
        acc[4] += blo(u.z) * w; acc[5] += bhi(u.z) * w;
        acc[6] += blo(u.w) * w; acc[7] += bhi(u.w) * w;
    }
    unsigned int o0 = (unsigned)f2b(acc[0]) | ((unsigned)f2b(acc[1]) << 16);
    unsigned int o1 = (unsigned)f2b(acc[2]) | ((unsigned)f2b(acc[3]) << 16);
    unsigned int o2 = (unsigned)f2b(acc[4]) | ((unsigned)f2b(acc[5]) << 16);
    unsigned int o3 = (unsigned)f2b(acc[6]) | ((unsigned)f2b(acc[7]) << 16);
    ((uint4*)outb)[(size_t)node * 64 + lane] = make_uint4(o0, o1, o2, o3);
}

// ---------------- fp32 GEMM (conv1): C[M,512] = A @ W + bias ----------------

#define BM 64
#define BN 64
#define BK 16

__global__ __launch_bounds__(256) void gemm_bias(const float* __restrict__ A, const float* __restrict__ W,
                                                 const float* __restrict__ bias, float* __restrict__ C) {
    __shared__ float Ast[BK][BM + 4];
    __shared__ float Ws[BK][BN + 4];
    int tid = threadIdx.x;
    int bm = blockIdx.x * BM;
    int bn = blockIdx.y * BN;
    int tx = tid & 15, ty = tid >> 4;
    float acc[4][4] = {};

    int ar = tid >> 2;
    int ak = (tid & 3) * 4;
    int wr = tid >> 4;
    int wc = (tid & 15) * 4;
    int arow = bm + ar;
    bool aval = arow < N_NODES;

    for (int k0 = 0; k0 < CH; k0 += BK) {
        float4 av = make_float4(0.f, 0.f, 0.f, 0.f);
        if (aval) av = *(const float4*)&A[(size_t)arow * CH + k0 + ak];
        float4 wv = *(const float4*)&W[(size_t)(k0 + wr) * CH + bn + wc];
        Ast[ak + 0][ar] = av.x;
        Ast[ak + 1][ar] = av.y;
        Ast[ak + 2][ar] = av.z;
        Ast[ak + 3][ar] = av.w;
        *(float4*)&Ws[wr][wc] = wv;
        __syncthreads();
        #pragma unroll
        for (int k = 0; k < BK; ++k) {
            float4 a = *(const float4*)&Ast[k][ty * 4];
            float4 w = *(const float4*)&Ws[k][tx * 4];
            float as[4] = {a.x, a.y, a.z, a.w};
            float wsv[4] = {w.x, w.y, w.z, w.w};
            #pragma unroll
            for (int i = 0; i < 4; ++i)
                #pragma unroll
                for (int j = 0; j < 4; ++j)
                    acc[i][j] += as[i] * wsv[j];
        }
        __syncthreads();
    }

    float4 bv = *(const float4*)&bias[bn + tx * 4];
    #pragma unroll
    for (int i = 0; i < 4; ++i) {
        int row = bm + ty * 4 + i;
        if (row < N_NODES) {
            float4 o = make_float4(acc[i][0] + bv.x, acc[i][1] + bv.y,
                                   acc[i][2] + bv.z, acc[i][3] + bv.w);
            *(float4*)&C[(size_t)row * CH + bn + tx * 4] = o;
        }
    }
}

// ---------------- bf16 MFMA GEMM (conv2): C[M,512] = Ab @ Wt^T + bias ----------------
// Ab row-major [M][512] bf16; Wt n-major [512 n][512 k] bf16.
// Block: 256 thr = 4 waves (2x2), tile BM2=128 x BN2=64, BK2=32.

#define BM2 128
#define BN2 64
#define BK2 32
#define LDP 40  // LDS row pitch in shorts (80 B -> 2-way bank aliasing only)

__global__ __launch_bounds__(256) void gemm_bf16(const unsigned short* __restrict__ Ab,
                                                 const unsigned short* __restrict__ Wt,
                                                 const float* __restrict__ bias,
                                                 float* __restrict__ C) {
    __shared__ short Alds[BM2 * LDP];
    __shared__ short Blds[BN2 * LDP];
    int tid = threadIdx.x;
    int lane = tid & 63;
    int wid = tid >> 6;
    int wm = wid & 1;   // 0/1 -> 64-row half
    int wn = wid >> 1;  // 0/1 -> 32-col half
    int bm = blockIdx.x * BM2;
    int bn = blockIdx.y * BN2;

    f32x4 acc[4][2] = {};

    int arow0 = tid >> 2, aq = tid & 3;   // A chunks: (row, quad), +64 rows second chunk
    int brow = tid >> 2, bq = tid & 3;    // B chunks: 64 rows x 4 quads = 256

    for (int k0 = 0; k0 < CH; k0 += BK2) {
        // stage A: 128 rows x 32 k (2 chunks/thread)
        #pragma unroll
        for (int h = 0; h < 2; ++h) {
            int row = arow0 + h * 64;
            int gr = bm + row;
            uint4 v = make_uint4(0u, 0u, 0u, 0u);
            if (gr < N_NODES) v = *(const uint4*)&Ab[(size_t)gr * CH + k0 + aq * 8];
            *(uint4*)&Alds[row * LDP + aq * 8] = v;
        }
        // stage B: 64 rows (n) x 32 k (1 chunk/thread)
        {
            uint4 v = *(const uint4*)&Wt[(size_t)(bn + brow) * CH + k0 + bq * 8];
            *(uint4*)&Blds[brow * LDP + bq * 8] = v;
        }
        __syncthreads();

        bf16x8 af[4], bf[2];
        #pragma unroll
        for (int mt = 0; mt < 4; ++mt)
            af[mt] = *(const bf16x8*)&Alds[(wm * 64 + mt * 16 + (lane & 15)) * LDP + (lane >> 4) * 8];
        #pragma unroll
        for (int nt = 0; nt < 2; ++nt)
            bf[nt] = *(const bf16x8*)&Blds[(wn * 32 + nt * 16 + (lane & 15)) * LDP + (lane >> 4) * 8];
        #pragma unroll
        for (int mt = 0; mt < 4; ++mt)
            #pragma unroll
            for (int nt = 0; nt < 2; ++nt)
                acc[mt][nt] = __builtin_amdgcn_mfma_f32_16x16x32_bf16(af[mt], bf[nt], acc[mt][nt], 0, 0, 0);
        __syncthreads();
    }

    // epilogue: C/D layout col=lane&15, row=(lane>>4)*4+r
    #pragma unroll
    for (int mt = 0; mt < 4; ++mt) {
        #pragma unroll
        for (int nt = 0; nt < 2; ++nt) {
            int col = bn + wn * 32 + nt * 16 + (lane & 15);
            float bv = bias[col];
            #pragma unroll
            for (int r = 0; r < 4; ++r) {
                int row = bm + wm * 64 + mt * 16 + (lane >> 4) * 4 + r;
                if (row < N_NODES) C[(size_t)row * CH + col] = acc[mt][nt][r] + bv;
            }
        }
    }
}

// ---------------- Softmax (+argmax), one wave per row ----------------

__global__ __launch_bounds__(256) void softmax_rows(const float* __restrict__ X, float* __restrict__ P,
                                                    float* __restrict__ preds) {
    int row = blockIdx.x * 4 + (threadIdx.x >> 6);
    int lane = threadIdx.x & 63;
    if (row >= N_NODES) return;
    const float4* x4 = (const float4*)(X + (size_t)row * CH);
    float4 v0 = x4[lane];
    float4 v1 = x4[lane + 64];
    float vals[8] = {v0.x, v0.y, v0.z, v0.w, v1.x, v1.y, v1.z, v1.w};
    float m = vals[0];
    int mi = lane * 4;
    #pragma unroll
    for (int j = 1; j < 8; ++j) {
        int c = (j < 4) ? (lane * 4 + j) : (256 + lane * 4 + (j - 4));
        if (vals[j] > m) { m = vals[j]; mi = c; }
    }
    #pragma unroll
    for (int d = 32; d > 0; d >>= 1) {
        float om = __shfl_xor(m, d, 64);
        int oi = __shfl_xor(mi, d, 64);
        if (om > m || (om == m && oi < mi)) { m = om; mi = oi; }
    }
    float s = 0.f;
    float ex[8];
    #pragma unroll
    for (int j = 0; j < 8; ++j) { ex[j] = __expf(vals[j] - m); s += ex[j]; }
    #pragma unroll
    for (int d = 32; d > 0; d >>= 1) s += __shfl_xor(s, d, 64);
    float inv = 1.0f / s;
    float4 o0 = make_float4(ex[0] * inv, ex[1] * inv, ex[2] * inv, ex[3] * inv);
    float4 o1 = make_float4(ex[4] * inv, ex[5] * inv, ex[6] * inv, ex[7] * inv);
    float4* p4 = (float4*)(P + (size_t)row * CH);
    p4[lane] = o0;
    p4[lane + 64] = o1;
    if (preds != nullptr && lane == 0) preds[row] = (float)mi;
}

// ---------------- launcher ----------------

extern "C" void kernel_launch(void* const* d_in, const int* in_sizes, int n_in,
                              void* d_out, int out_size, void* d_ws, size_t ws_size,
                              hipStream_t stream) {
    const float* x  = (const float*)d_in[0];
    const int*   e1 = (const int*)d_in[1];
    const int*   e2 = (const int*)d_in[2];
    const float* W1 = (const float*)d_in[3];
    const float* b1 = (const float*)d_in[4];
    const float* W2 = (const float*)d_in[5];
    const float* b2 = (const float*)d_in[6];

    float* out     = (float*)d_out;
    float* logits1 = out;
    float* logits2 = out + (size_t)N_NODES * CH;
    float* preds   = out + 2 * (size_t)N_NODES * CH;

    const size_t NEED = 109600016;
    if (ws_size < NEED) return;

    char* ws = (char*)d_ws;
    float* A      = (float*)(ws);                 // 102.4 MB fp32 scratch
    int*   cnt    = (int*)(ws + 102400000);
    int*   offs   = (int*)(ws + 102600000);
    int*   cursor = (int*)(ws + 102800016);
    float* dinv   = (float*)(ws + 103000016);
    int*   srcs   = (int*)(ws + 103200016);
    float* enorm  = (float*)(ws + 106400016);

    // conv2 bf16 scratch carved from regions free during conv2:
    unsigned short* xb  = (unsigned short*)logits1;                    // 51.2 MB in logits1 region
    unsigned short* Wtb = (unsigned short*)((char*)logits1 + 51200000);// 0.5 MB, also logits1 region
    unsigned short* h1b = (unsigned short*)A;                          // 51.2 MB
    unsigned short* h2b = (unsigned short*)((char*)A + 51200000);      // 51.2 MB

    // ================= conv2 (bf16 path) first =================
    {
        hipMemsetAsync(cnt, 0, N_NODES * sizeof(int), stream);
        hipMemsetAsync(cursor, 0, N_NODES * sizeof(int), stream);
        count_col<<<(N_EDGES + 255) / 256, 256, 0, stream>>>(e2 + N_EDGES, cnt);
        make_dinv<<<(N_NODES + 255) / 256, 256, 0, stream>>>(cnt, dinv);
        scan_offsets<<<1, 1024, 0, stream>>>(cnt, offs);
        fill_csr<<<(N_EDGES + 255) / 256, 256, 0, stream>>>(e2, offs, cursor, dinv, srcs, enorm);

        convert_x_bf16<<<(N_NODES * CH / 8 + 255) / 256, 256, 0, stream>>>(x, xb);
        convert_w_t<<<(512 * 512) / 256, 256, 0, stream>>>(W2, Wtb);

        propagate_bf16<<<N_NODES / 2, 128, 0, stream>>>(xb, h1b, offs, srcs, enorm, dinv);
        propagate_bf16<<<N_NODES / 2, 128, 0, stream>>>(h1b, h2b, offs, srcs, enorm, dinv);

        dim3 g((N_NODES + BM2 - 1) / BM2, CH / BN2);
        gemm_bf16<<<g, 256, 0, stream>>>(h2b, Wtb, b2, logits2);
        softmax_rows<<<N_NODES / 4, 256, 0, stream>>>(logits2, logits2, nullptr);
    }

    // ================= conv1 (fp32 path, argmax-exact) =================
    {
        hipMemsetAsync(cnt, 0, N_NODES * sizeof(int), stream);
        hipMemsetAsync(cursor, 0, N_NODES * sizeof(int), stream);
        count_col<<<(N_EDGES + 255) / 256, 256, 0, stream>>>(e1 + N_EDGES, cnt);
        make_dinv<<<(N_NODES + 255) / 256, 256, 0, stream>>>(cnt, dinv);
        scan_offsets<<<1, 1024, 0, stream>>>(cnt, offs);
        fill_csr<<<(N_EDGES + 255) / 256, 256, 0, stream>>>(e1, offs, cursor, dinv, srcs, enorm);

        propagate<<<N_NODES, 128, 0, stream>>>(x, logits1, offs, srcs, enorm, dinv);
        propagate<<<N_NODES, 128, 0, stream>>>(logits1, A, offs, srcs, enorm, dinv);

        dim3 g((N_NODES + BM - 1) / BM, CH / BN);
        gemm_bias<<<g, 256, 0, stream>>>(A, W1, b1, logits1);
        softmax_rows<<<N_NODES / 4, 256, 0, stream>>>(logits1, logits1, preds);
    }
}